// Round 7
// baseline (99.711 us; speedup 1.0000x reference)
//
#include <hip/hip_runtime.h>
#include <math.h>

// Problem constants
#define NB 1024
#define NC 5994
#define NCP 6144   // padded row count for wb (48 c-tiles of 128)
#define NK 512
#define NA 3
#define NT 48      // total K-steps: NA * (NK/32)
#define SCALE_F 30.0f
#define NV 94      // ceil(NC/64) values per lane in row_loss

// Margin constants
#define COS_M_F 0.9800665778412416f
#define SIN_M_F 0.19866933079506122f
#define TH_F (-0.9800665778412416f)
#define MM_F 0.039733866159012244f
#define SUB_COS_M_F 0.9982005399352042f
#define SUB_SIN_M_F (-0.05996400647944459f)
#define SUB_TH_F (-0.9982005399352042f)
#define SUB_MM_F 0.0035978403887666754f

typedef __attribute__((ext_vector_type(8))) short short8;   // 8 bf16 (4 VGPRs)
typedef __attribute__((ext_vector_type(4))) float f32x4;    // MFMA accumulator

__device__ __forceinline__ float waveReduceSum(float v) {
#pragma unroll
  for (int off = 32; off > 0; off >>= 1) v += __shfl_down(v, off);
  return v;
}

__device__ __forceinline__ void waveArgMax(float& v, int& i) {
#pragma unroll
  for (int off = 32; off > 0; off >>= 1) {
    float ov = __shfl_down(v, off);
    int oi = __shfl_down(i, off);
    if (ov > v || (ov == v && (unsigned)oi < (unsigned)i)) { v = ov; i = oi; }
  }
}

__device__ __forceinline__ ushort f2bf(float f) {
  unsigned u = __float_as_uint(f);
  u += 0x7FFFu + ((u >> 16) & 1u);
  return (ushort)(u >> 16);
}

__device__ __forceinline__ void load_lds16(const ushort* g, ushort* l) {
  __builtin_amdgcn_global_load_lds(
      (const __attribute__((address_space(1))) unsigned int*)g,
      (__attribute__((address_space(3))) unsigned int*)l, 16, 0, 0);
}

// Fused L2-normalize + bf16 convert. 4 rows per 256-thread block (1 row/wave).
__global__ __launch_bounds__(256) void norm_convert(const float* __restrict__ x,
                                                    const float* __restrict__ w,
                                                    ushort* __restrict__ xb,
                                                    ushort* __restrict__ wb) {
  const int row = blockIdx.x * 4 + (threadIdx.x >> 6);
  const int lane = threadIdx.x & 63;
  const float* src;
  ushort* dst;
  if (row < NB) {
    src = x + (size_t)row * NK;
    dst = xb + (size_t)row * NK;
  } else {
    const int r = row - NB;           // 0 .. NA*NCP-1
    const int a = r / NCP, c = r % NCP;
    dst = wb + (size_t)r * NK;
    if (c >= NC) {                    // zero-fill padding row
      ushort4 z = {0, 0, 0, 0};
      *(ushort4*)(dst + lane * 4) = z;
      *(ushort4*)(dst + 256 + lane * 4) = z;
      return;
    }
    src = w + ((size_t)a * NC + c) * NK;
  }
  const float4 v0 = *(const float4*)(src + lane * 4);
  const float4 v1 = *(const float4*)(src + 256 + lane * 4);
  float ss = v0.x * v0.x + v0.y * v0.y + v0.z * v0.z + v0.w * v0.w +
             v1.x * v1.x + v1.y * v1.y + v1.z * v1.z + v1.w * v1.w;
  ss = waveReduceSum(ss);
  ss = __shfl(ss, 0);
  const float rn = 1.0f / fmaxf(sqrtf(ss), 1e-12f);
  ushort4 o0 = {f2bf(v0.x * rn), f2bf(v0.y * rn), f2bf(v0.z * rn), f2bf(v0.w * rn)};
  ushort4 o1 = {f2bf(v1.x * rn), f2bf(v1.y * rn), f2bf(v1.z * rn), f2bf(v1.w * rn)};
  *(ushort4*)(dst + lane * 4) = o0;
  *(ushort4*)(dst + 256 + lane * 4) = o1;
}

// cosine[b,c] = max_a dot(xn[b,:], wn[a,c,:])  via bf16 MFMA, fp32 accum.
// R5-proven sync structure: 64x128 tile, 2 waves, double-buffered LDS,
// one barrier pair per K-step. NEW (this round): k-major per-16x32-sub-block
// LDS layout. Lane l of sub-block s supplies global (row s*16 + (l&15),
// cols (l>>4)*8..+7), landing at linear LDS offset s*512 + l*8 -- which is
// exactly where lane l's MFMA fragment read looks. Fragment reads are thus
// a linear 1024B wave sweep: 2 lanes/bank = conflict-free (m136), replacing
// the previous 8-way conflict (16 lanes @ 64B row stride).
// Grid 16x48 = 768 = 3 blocks/CU; XCD swizzle keeps each B-panel's 16
// sharers on one XCD L2 (proven: FETCH 84->15 MB).
__global__ __launch_bounds__(128) void cos_gemm_mfma(const ushort* __restrict__ Xb,
                                                     const ushort* __restrict__ Wb,
                                                     float* __restrict__ cosine) {
  __shared__ ushort sA0[64 * 32];   // 4 KB each
  __shared__ ushort sA1[64 * 32];
  __shared__ ushort sB0[128 * 32];  // 8 KB each
  __shared__ ushort sB1[128 * 32];
  const int tid = threadIdx.x;
  const int lane = tid & 63;
  const int w = tid >> 6;           // 0..1

  // swizzle: id = (cx&7) + 8*by + 128*(cx>>3)  (bijective on 8*16*6 = 768)
  const int id = blockIdx.x;
  const int cx = (id & 7) + ((id >> 7) << 3);   // 0..47
  const int by = (id >> 3) & 15;                // 0..15
  const int b0 = by * 64;
  const int c0 = cx * 128;

  const int r = lane & 15;
  const int kg = lane >> 4;
  const int l8 = lane * 8;
  // staging sources (k-major permutation): wave w stages A sub-blocks
  // {2w, 2w+1} (rows w*32 .. w*32+31) and B sub-blocks {4w..4w+3}
  // (rows w*64 .. w*64+63).
  const ushort* gA = Xb + (size_t)(b0 + w * 32 + r) * NK + kg * 8;
  const ushort* gB = Wb + (size_t)(c0 + w * 64 + r) * NK + kg * 8;
  const int ldsA = w * 1024;        // ushort offset: sub-block 2w
  const int ldsB = w * 2048;        // ushort offset: sub-block 4w
  const int w4 = w * 4;

  f32x4 best[4][4];
  f32x4 acc[4][4];
#pragma unroll
  for (int i = 0; i < 4; ++i)
#pragma unroll
    for (int j = 0; j < 4; ++j) {
#pragma unroll
      for (int q = 0; q < 4; ++q) best[i][j][q] = -INFINITY;
      acc[i][j] = (f32x4)(0.f);
    }

  // prologue: stage t=0 into buffer 0
  load_lds16(gA, (ushort*)sA0 + ldsA);
  load_lds16(gA + 16 * NK, (ushort*)sA0 + ldsA + 512);
#pragma unroll
  for (int j = 0; j < 4; ++j)
    load_lds16(gB + (size_t)j * 16 * NK, (ushort*)sB0 + ldsB + j * 512);
  __syncthreads();

#define GEMM_BODY(T, SAr, SBr, SAw, SBw)                                        \
  {                                                                             \
    const int t_ = (T);                                                         \
    if (t_ + 1 < NT) {                                                          \
      const int tn = t_ + 1;                                                    \
      const int k0 = (tn & 15) << 5;                                            \
      const size_t boff = (size_t)(tn >> 4) * NCP * NK + k0;                    \
      load_lds16(gA + k0, (ushort*)SAw + ldsA);                                 \
      load_lds16(gA + k0 + 16 * NK, (ushort*)SAw + ldsA + 512);                 \
      _Pragma("unroll") for (int j = 0; j < 4; ++j)                             \
          load_lds16(gB + boff + (size_t)j * 16 * NK,                           \
                     (ushort*)SBw + ldsB + j * 512);                            \
    }                                                                           \
    short8 af[4], bf[4];                                                        \
    _Pragma("unroll") for (int mi = 0; mi < 4; ++mi)                            \
        af[mi] = *(const short8*)&SAr[mi * 512 + l8];                           \
    _Pragma("unroll") for (int ni = 0; ni < 4; ++ni)                            \
        bf[ni] = *(const short8*)&SBr[(w4 + ni) * 512 + l8];                    \
    _Pragma("unroll") for (int mi = 0; mi < 4; ++mi)                            \
        _Pragma("unroll") for (int ni = 0; ni < 4; ++ni)                        \
            acc[mi][ni] = __builtin_amdgcn_mfma_f32_16x16x32_bf16(              \
                af[mi], bf[ni], acc[mi][ni], 0, 0, 0);                          \
    if ((t_ & 15) == 15) {                                                      \
      _Pragma("unroll") for (int i = 0; i < 4; ++i)                             \
          _Pragma("unroll") for (int j = 0; j < 4; ++j) {                       \
        _Pragma("unroll") for (int q = 0; q < 4; ++q)                           \
            best[i][j][q] = fmaxf(best[i][j][q], acc[i][j][q]);                 \
        acc[i][j] = (f32x4)(0.f);                                               \
      }                                                                         \
    }                                                                           \
    __syncthreads();                                                            \
  }

  for (int t = 0; t < NT; t += 2) {
    GEMM_BODY(t, sA0, sB0, sA1, sB1)
    GEMM_BODY(t + 1, sA1, sB1, sA0, sB0)
  }
#undef GEMM_BODY

  // C/D layout: col = lane&15, row = (lane>>4)*4 + q   [measured m89/m91]
  const int q4 = (lane >> 4) * 4;
#pragma unroll
  for (int ni = 0; ni < 4; ++ni) {
    const int col = c0 + w * 64 + ni * 16 + r;
    if (col < NC) {
#pragma unroll
      for (int mi = 0; mi < 4; ++mi) {
        const int row0 = b0 + mi * 16 + q4;
#pragma unroll
        for (int q = 0; q < 4; ++q)
          cosine[(size_t)(row0 + q) * NC + col] = best[mi][ni][q];
      }
    }
  }
}

// Per-row loss: ONE WAVE per row (4 waves/block), packed stride-NC rows,
// scalar coalesced loads (94 values/lane), all reductions wave-local
// shuffles. No LDS, no barriers. Top0..top4 are killed from v[] during
// extraction and re-added exactly once in S (accounting verified).
__global__ __launch_bounds__(256) void row_loss(const float* __restrict__ cosine,
                                                const int* __restrict__ label,
                                                float* __restrict__ loss_b,
                                                float* __restrict__ corr_b) {
  const int row = blockIdx.x * 4 + (threadIdx.x >> 6);
  const int lane = threadIdx.x & 63;
  const int lab = label[row];
  const float* rp = cosine + (size_t)row * NC;

  float v[NV];
#pragma unroll
  for (int e = 0; e < NV; ++e) {
    const int idx = e * 64 + lane;
    v[e] = (idx < NC) ? rp[idx] : -INFINITY;
  }

  // label cosine: owner lane = lab & 63, slot = lab >> 6
  float cl = -INFINITY;
#pragma unroll
  for (int e = 0; e < NV; ++e)
    if (e * 64 + lane == lab) cl = v[e];
  const float cosL = __shfl(cl, lab & 63);

  // top-6 extraction (value desc, index asc — matches stable top_k)
  float topv[6];
  int topi[6];
#pragma unroll
  for (int e6 = 0; e6 < 6; ++e6) {
    float bv = -INFINITY;
    int bi = 0x7FFFFFFF;
#pragma unroll
    for (int e = 0; e < NV; ++e)
      if (v[e] > bv) { bv = v[e]; bi = e * 64 + lane; }
    waveArgMax(bv, bi);
    bv = __shfl(bv, 0);
    bi = __shfl(bi, 0);
    topv[e6] = bv;
    topi[e6] = bi;
    if (e6 < 5 && (bi & 63) == lane) {   // owner lane kills its copy
      const int ke = bi >> 6;
#pragma unroll
      for (int e = 0; e < NV; ++e)
        if (e == ke) v[e] = -INFINITY;
    }
  }
  const float maxv = topv[0];

  // shifted exp-sum: v[] is missing top0..top4 (killed); re-add them below.
  float ps = 0.f;
#pragma unroll
  for (int e = 0; e < NV; ++e) ps += __expf(SCALE_F * (v[e] - maxv));
  ps = waveReduceSum(ps);

  if (lane == 0) {
    float S = ps;
#pragma unroll
    for (int e6 = 0; e6 < 5; ++e6) S += __expf(SCALE_F * (topv[e6] - maxv));
    const float m = SCALE_F * maxv;
    const float sineL = sqrtf(fminf(fmaxf(1.f - cosL * cosL, 0.f), 1.f));
    const float phiL = (cosL - TH_F > 0.f) ? (cosL * COS_M_F - sineL * SIN_M_F) : (cosL - MM_F);
    float adj = __expf(SCALE_F * phiL - m) - __expf(SCALE_F * cosL - m);
    int cnt = 0;
#pragma unroll
    for (int e = 0; e < 6; ++e) {
      if (topi[e] == lab || cnt >= 5) continue;
      const float c = topv[e];
      const float sine = sqrtf(fminf(fmaxf(1.f - c * c, 0.f), 1.f));
      const float sp = (c - SUB_TH_F > 0.f) ? (c * SUB_COS_M_F - sine * SUB_SIN_M_F) : (c - SUB_MM_F);
      adj += __expf(SCALE_F * sp - m) - __expf(SCALE_F * c - m);
      ++cnt;
    }
    const float Sp = S + adj;
    loss_b[row] = (logf(Sp) + m) - SCALE_F * phiL;
    corr_b[row] = (topi[0] == lab) ? 1.f : 0.f;
  }
}

__global__ __launch_bounds__(256) void finalize(const float* __restrict__ loss_b,
                                                const float* __restrict__ corr_b,
                                                float* __restrict__ out) {
  const int tid = threadIdx.x;
  float ls = 0.f, cs = 0.f;
  for (int i = tid; i < NB; i += 256) { ls += loss_b[i]; cs += corr_b[i]; }
  ls = waveReduceSum(ls);
  cs = waveReduceSum(cs);
  __shared__ float sl[4], sc[4];
  if ((tid & 63) == 0) { sl[tid >> 6] = ls; sc[tid >> 6] = cs; }
  __syncthreads();
  if (tid == 0) {
    const float L = sl[0] + sl[1] + sl[2] + sl[3];
    const float Cr = sc[0] + sc[1] + sc[2] + sc[3];
    out[0] = L / (float)NB;
    out[1] = Cr / (float)NB * 100.f;
  }
}

extern "C" void kernel_launch(void* const* d_in, const int* in_sizes, int n_in,
                              void* d_out, int out_size, void* d_ws, size_t ws_size,
                              hipStream_t stream) {
  const float* x = (const float*)d_in[0];      // [1024, 512]
  const float* w = (const float*)d_in[1];      // [3, 5994, 512]
  const int* label = (const int*)d_in[2];      // [1024]
  float* out = (float*)d_out;                  // [2] = {loss, prec1}
  char* ws = (char*)d_ws;

  // workspace layout (bytes) — identical footprint to R5 (proven in-bounds):
  ushort* xb = (ushort*)ws;                                    // 1,048,576
  ushort* wb = (ushort*)(ws + 1048576);                        // 18,874,368
  float* cosine = (float*)(ws + 1048576 + 18874368);           // 24,551,424 (packed, stride 5994)
  // loss_b/corr_b reuse the xb region (xb dead after cos_gemm_mfma)
  float* loss_b = (float*)ws;
  float* corr_b = (float*)(ws + 4096);

  norm_convert<<<(NB + NA * NCP) / 4, 256, 0, stream>>>(x, w, xb, wb);
  cos_gemm_mfma<<<16 * 48, 128, 0, stream>>>(xb, wb, cosine);
  row_loss<<<NB / 4, 256, 0, stream>>>(cosine, label, loss_b, corr_b);
  finalize<<<1, 256, 0, stream>>>(loss_b, corr_b, out);
}

// Round 8
// 67.899 us; speedup vs baseline: 1.4685x; 1.4685x over previous
//
#include <hip/hip_runtime.h>
#include <math.h>

// Problem constants
#define NB 1024
#define NC 5994
#define NCP 6144   // padded row count for wb (48 c-tiles of 128)
#define NK 512
#define NA 3
#define NT 48      // total K-steps: NA * (NK/32)
#define SCALE_F 30.0f
#define NPT 24     // ceil(NC/256) for row_loss

// Margin constants
#define COS_M_F 0.9800665778412416f
#define SIN_M_F 0.19866933079506122f
#define TH_F (-0.9800665778412416f)
#define MM_F 0.039733866159012244f
#define SUB_COS_M_F 0.9982005399352042f
#define SUB_SIN_M_F (-0.05996400647944459f)
#define SUB_TH_F (-0.9982005399352042f)
#define SUB_MM_F 0.0035978403887666754f

typedef __attribute__((ext_vector_type(8))) short short8;   // 8 bf16 (4 VGPRs)
typedef __attribute__((ext_vector_type(4))) float f32x4;    // MFMA accumulator

__device__ __forceinline__ float waveReduceSum(float v) {
#pragma unroll
  for (int off = 32; off > 0; off >>= 1) v += __shfl_down(v, off);
  return v;
}

__device__ __forceinline__ void waveArgMax(float& v, int& i) {
#pragma unroll
  for (int off = 32; off > 0; off >>= 1) {
    float ov = __shfl_down(v, off);
    int oi = __shfl_down(i, off);
    if (ov > v || (ov == v && (unsigned)oi < (unsigned)i)) { v = ov; i = oi; }
  }
}

__device__ __forceinline__ ushort f2bf(float f) {
  unsigned u = __float_as_uint(f);
  u += 0x7FFFu + ((u >> 16) & 1u);
  return (ushort)(u >> 16);
}

__device__ __forceinline__ void load_lds16(const ushort* g, ushort* l) {
  __builtin_amdgcn_global_load_lds(
      (const __attribute__((address_space(1))) unsigned int*)g,
      (__attribute__((address_space(3))) unsigned int*)l, 16, 0, 0);
}

// Fused L2-normalize + bf16 convert. 4 rows per 256-thread block (1 row/wave).
__global__ __launch_bounds__(256) void norm_convert(const float* __restrict__ x,
                                                    const float* __restrict__ w,
                                                    ushort* __restrict__ xb,
                                                    ushort* __restrict__ wb) {
  const int row = blockIdx.x * 4 + (threadIdx.x >> 6);
  const int lane = threadIdx.x & 63;
  const float* src;
  ushort* dst;
  if (row < NB) {
    src = x + (size_t)row * NK;
    dst = xb + (size_t)row * NK;
  } else {
    const int r = row - NB;           // 0 .. NA*NCP-1
    const int a = r / NCP, c = r % NCP;
    dst = wb + (size_t)r * NK;
    if (c >= NC) {                    // zero-fill padding row
      ushort4 z = {0, 0, 0, 0};
      *(ushort4*)(dst + lane * 4) = z;
      *(ushort4*)(dst + 256 + lane * 4) = z;
      return;
    }
    src = w + ((size_t)a * NC + c) * NK;
  }
  const float4 v0 = *(const float4*)(src + lane * 4);
  const float4 v1 = *(const float4*)(src + 256 + lane * 4);
  float ss = v0.x * v0.x + v0.y * v0.y + v0.z * v0.z + v0.w * v0.w +
             v1.x * v1.x + v1.y * v1.y + v1.z * v1.z + v1.w * v1.w;
  ss = waveReduceSum(ss);
  ss = __shfl(ss, 0);
  const float rn = 1.0f / fmaxf(sqrtf(ss), 1e-12f);
  ushort4 o0 = {f2bf(v0.x * rn), f2bf(v0.y * rn), f2bf(v0.z * rn), f2bf(v0.w * rn)};
  ushort4 o1 = {f2bf(v1.x * rn), f2bf(v1.y * rn), f2bf(v1.z * rn), f2bf(v1.w * rn)};
  *(ushort4*)(dst + lane * 4) = o0;
  *(ushort4*)(dst + 256 + lane * 4) = o1;
}

// cosine[b,c] = max_a dot(xn[b,:], wn[a,c,:])  via bf16 MFMA, fp32 accum.
// R5 sync structure (64x128 tile, 2 waves, double-buffer, 1 barrier pair /
// K-step, 768-block grid, XCD swizzle) + slot-ROTATION LDS swizzle:
//  - staging lane quad 4j..4j+3 reads row j's 64B contiguous (VMEM-coalesced,
//    R5-proven), but chunk order rotated by (row>>1): srcKg = ((l&3)-(l>>3))&3
//  - fragment read at  r*32 + (((kg + (r>>1))&3)*8): per-16-lane phase, rows
//    {0,8},{1,9},... pairwise share a bank quad -> 2 words/bank = conflict-
//    free (m136), replacing R5's 8-way conflict. Both sides optimal.
__global__ __launch_bounds__(128) void cos_gemm_mfma(const ushort* __restrict__ Xb,
                                                     const ushort* __restrict__ Wb,
                                                     float* __restrict__ cosine) {
  __shared__ ushort sA0[64 * 32];   // 4 KB each
  __shared__ ushort sA1[64 * 32];
  __shared__ ushort sB0[128 * 32];  // 8 KB each
  __shared__ ushort sB1[128 * 32];
  const int tid = threadIdx.x;
  const int lane = tid & 63;
  const int w = tid >> 6;           // 0..1

  // swizzle: id = (cx&7) + 8*by + 128*(cx>>3)  (bijective on 8*16*6 = 768)
  const int id = blockIdx.x;
  const int cx = (id & 7) + ((id >> 7) << 3);   // 0..47
  const int by = (id >> 3) & 15;                // 0..15
  const int b0 = by * 64;
  const int c0 = cx * 128;

  // staging source: row-within-subblock = lane>>2 (quads contiguous),
  // chunk rotated: srcKg = ((lane&3) - ((lane>>3)&3)) & 3
  const int lrow = lane >> 2;
  const int skg = ((lane & 3) - ((lane >> 3) & 3)) & 3;
  const ushort* gA = Xb + (size_t)(b0 + w * 32 + lrow) * NK + skg * 8;
  const ushort* gB = Wb + (size_t)(c0 + w * 64 + lrow) * NK + skg * 8;
  const int ldsA = w * 1024;        // ushort offset: A sub-block 2w
  const int ldsB = w * 2048;        // ushort offset: B sub-block 4w
  const int w4 = w * 4;

  // fragment-read offset: r*32 + (((kg + (r>>1)) & 3) * 8)
  const int r = lane & 15;
  const int kg = lane >> 4;
  const int rdoff = r * 32 + (((kg + (r >> 1)) & 3) * 8);

  f32x4 best[4][4];
  f32x4 acc[4][4];
#pragma unroll
  for (int i = 0; i < 4; ++i)
#pragma unroll
    for (int j = 0; j < 4; ++j) {
#pragma unroll
      for (int q = 0; q < 4; ++q) best[i][j][q] = -INFINITY;
      acc[i][j] = (f32x4)(0.f);
    }

  // prologue: stage t=0 into buffer 0
  load_lds16(gA, (ushort*)sA0 + ldsA);
  load_lds16(gA + 16 * NK, (ushort*)sA0 + ldsA + 512);
#pragma unroll
  for (int j = 0; j < 4; ++j)
    load_lds16(gB + (size_t)j * 16 * NK, (ushort*)sB0 + ldsB + j * 512);
  __syncthreads();

#define GEMM_BODY(T, SAr, SBr, SAw, SBw)                                        \
  {                                                                             \
    const int t_ = (T);                                                         \
    if (t_ + 1 < NT) {                                                          \
      const int tn = t_ + 1;                                                    \
      const int k0 = (tn & 15) << 5;                                            \
      const size_t boff = (size_t)(tn >> 4) * NCP * NK + k0;                    \
      load_lds16(gA + k0, (ushort*)SAw + ldsA);                                 \
      load_lds16(gA + k0 + 16 * NK, (ushort*)SAw + ldsA + 512);                 \
      _Pragma("unroll") for (int j = 0; j < 4; ++j)                             \
          load_lds16(gB + boff + (size_t)j * 16 * NK,                           \
                     (ushort*)SBw + ldsB + j * 512);                            \
    }                                                                           \
    short8 af[4], bf[4];                                                        \
    _Pragma("unroll") for (int mi = 0; mi < 4; ++mi)                            \
        af[mi] = *(const short8*)&SAr[mi * 512 + rdoff];                        \
    _Pragma("unroll") for (int ni = 0; ni < 4; ++ni)                            \
        bf[ni] = *(const short8*)&SBr[(w4 + ni) * 512 + rdoff];                 \
    _Pragma("unroll") for (int mi = 0; mi < 4; ++mi)                            \
        _Pragma("unroll") for (int ni = 0; ni < 4; ++ni)                        \
            acc[mi][ni] = __builtin_amdgcn_mfma_f32_16x16x32_bf16(              \
                af[mi], bf[ni], acc[mi][ni], 0, 0, 0);                          \
    if ((t_ & 15) == 15) {                                                      \
      _Pragma("unroll") for (int i = 0; i < 4; ++i)                             \
          _Pragma("unroll") for (int j = 0; j < 4; ++j) {                       \
        _Pragma("unroll") for (int q = 0; q < 4; ++q)                           \
            best[i][j][q] = fmaxf(best[i][j][q], acc[i][j][q]);                 \
        acc[i][j] = (f32x4)(0.f);                                               \
      }                                                                         \
    }                                                                           \
    __syncthreads();                                                            \
  }

  for (int t = 0; t < NT; t += 2) {
    GEMM_BODY(t, sA0, sB0, sA1, sB1)
    GEMM_BODY(t + 1, sA1, sB1, sA0, sB0)
  }
#undef GEMM_BODY

  // C/D layout: col = lane&15, row = (lane>>4)*4 + q   [measured m89/m91]
  const int q4 = (lane >> 4) * 4;
#pragma unroll
  for (int ni = 0; ni < 4; ++ni) {
    const int col = c0 + w * 64 + ni * 16 + r;
    if (col < NC) {
#pragma unroll
      for (int mi = 0; mi < 4; ++mi) {
        const int row0 = b0 + mi * 16 + q4;
#pragma unroll
        for (int q = 0; q < 4; ++q)
          cosine[(size_t)(row0 + q) * NC + col] = best[mi][ni][q];
      }
    }
  }
}

// Per-row loss (R5-proven): 256 threads/row, register-resident 24 elems/thread,
// argmax -> exp-sum -> 5 masked extraction passes via per-thread bitmap.
__global__ __launch_bounds__(256) void row_loss(const float* __restrict__ cosine,
                                                const int* __restrict__ label,
                                                float* __restrict__ loss_b,
                                                float* __restrict__ corr_b) {
  __shared__ float swv[4];
  __shared__ int swi[4];
  __shared__ float s_red[4];
  __shared__ float s_maxv;
  __shared__ float s_cosL;
  __shared__ float topv[6];
  __shared__ int topi[6];

  const int b = blockIdx.x, tid = threadIdx.x;
  const int wv = tid >> 6;
  const int lab = label[b];
  const float* row = cosine + (size_t)b * NC;

  float v[NPT];
  float bv = -INFINITY;
  int bi = -1;
#pragma unroll
  for (int j = 0; j < NPT; ++j) {
    const int i = tid + j * 256;
    v[j] = (i < NC) ? row[i] : -INFINITY;
    if (v[j] > bv) { bv = v[j]; bi = i; }
  }
  if (tid == (lab & 255)) s_cosL = v[lab >> 8];
  waveArgMax(bv, bi);
  if ((tid & 63) == 0) { swv[wv] = bv; swi[wv] = bi; }
  __syncthreads();
  if (tid == 0) {
    float mv = swv[0]; int mi = swi[0];
    for (int q = 1; q < 4; ++q)
      if (swv[q] > mv || (swv[q] == mv && (unsigned)swi[q] < (unsigned)mi)) { mv = swv[q]; mi = swi[q]; }
    s_maxv = mv; topv[0] = mv; topi[0] = mi;
  }
  __syncthreads();
  const float maxv = s_maxv;

  float ps = 0.f;
#pragma unroll
  for (int j = 0; j < NPT; ++j) ps += __expf(SCALE_F * (v[j] - maxv));
  ps = waveReduceSum(ps);
  if ((tid & 63) == 0) s_red[wv] = ps;

  unsigned excl = 0;
  {
    const int wi = topi[0];
    if ((wi & 255) == tid) excl |= 1u << (wi >> 8);
  }

  for (int e = 1; e < 6; ++e) {
    float lv = -INFINITY;
    int li = -1;
#pragma unroll
    for (int j = 0; j < NPT; ++j)
      if (!((excl >> j) & 1u) && v[j] > lv) { lv = v[j]; li = tid + j * 256; }
    waveArgMax(lv, li);
    if ((tid & 63) == 0) { swv[wv] = lv; swi[wv] = li; }
    __syncthreads();
    if (tid == 0) {
      float mv = swv[0]; int mi = swi[0];
      for (int q = 1; q < 4; ++q)
        if (swv[q] > mv || (swv[q] == mv && (unsigned)swi[q] < (unsigned)mi)) { mv = swv[q]; mi = swi[q]; }
      topv[e] = mv; topi[e] = mi;
    }
    __syncthreads();
    const int wi = topi[e];
    if ((wi & 255) == tid) excl |= 1u << (wi >> 8);
  }

  if (tid == 0) {
    const float S = s_red[0] + s_red[1] + s_red[2] + s_red[3];
    const float m = SCALE_F * maxv;
    const float cosL = s_cosL;
    const float sineL = sqrtf(fminf(fmaxf(1.f - cosL * cosL, 0.f), 1.f));
    const float phiL = (cosL - TH_F > 0.f) ? (cosL * COS_M_F - sineL * SIN_M_F) : (cosL - MM_F);
    float adj = __expf(SCALE_F * phiL - m) - __expf(SCALE_F * cosL - m);
    int cnt = 0;
    for (int e = 0; e < 6 && cnt < 5; ++e) {
      if (topi[e] == lab) continue;
      const float c = topv[e];
      const float sine = sqrtf(fminf(fmaxf(1.f - c * c, 0.f), 1.f));
      const float sp = (c - SUB_TH_F > 0.f) ? (c * SUB_COS_M_F - sine * SUB_SIN_M_F) : (c - SUB_MM_F);
      adj += __expf(SCALE_F * sp - m) - __expf(SCALE_F * c - m);
      ++cnt;
    }
    const float Sp = S + adj;
    loss_b[b] = (logf(Sp) + m) - SCALE_F * phiL;
    corr_b[b] = (topi[0] == lab) ? 1.f : 0.f;
  }
}

__global__ __launch_bounds__(256) void finalize(const float* __restrict__ loss_b,
                                                const float* __restrict__ corr_b,
                                                float* __restrict__ out) {
  const int tid = threadIdx.x;
  float ls = 0.f, cs = 0.f;
  for (int i = tid; i < NB; i += 256) { ls += loss_b[i]; cs += corr_b[i]; }
  ls = waveReduceSum(ls);
  cs = waveReduceSum(cs);
  __shared__ float sl[4], sc[4];
  if ((tid & 63) == 0) { sl[tid >> 6] = ls; sc[tid >> 6] = cs; }
  __syncthreads();
  if (tid == 0) {
    const float L = sl[0] + sl[1] + sl[2] + sl[3];
    const float Cr = sc[0] + sc[1] + sc[2] + sc[3];
    out[0] = L / (float)NB;
    out[1] = Cr / (float)NB * 100.f;
  }
}

extern "C" void kernel_launch(void* const* d_in, const int* in_sizes, int n_in,
                              void* d_out, int out_size, void* d_ws, size_t ws_size,
                              hipStream_t stream) {
  const float* x = (const float*)d_in[0];      // [1024, 512]
  const float* w = (const float*)d_in[1];      // [3, 5994, 512]
  const int* label = (const int*)d_in[2];      // [1024]
  float* out = (float*)d_out;                  // [2] = {loss, prec1}
  char* ws = (char*)d_ws;

  // workspace layout (bytes) — identical footprint to R5 (proven in-bounds):
  ushort* xb = (ushort*)ws;                                    // 1,048,576
  ushort* wb = (ushort*)(ws + 1048576);                        // 18,874,368
  float* cosine = (float*)(ws + 1048576 + 18874368);           // 24,551,424 (packed, stride 5994)
  // loss_b/corr_b reuse the xb region (xb dead after cos_gemm_mfma)
  float* loss_b = (float*)ws;
  float* corr_b = (float*)(ws + 4096);

  norm_convert<<<(NB + NA * NCP) / 4, 256, 0, stream>>>(x, w, xb, wb);
  cos_gemm_mfma<<<16 * 48, 128, 0, stream>>>(xb, wb, cosine);
  row_loss<<<NB, 256, 0, stream>>>(cosine, label, loss_b, corr_b);
  finalize<<<1, 256, 0, stream>>>(loss_b, corr_b, out);
}